// Round 3
// baseline (601.693 us; speedup 1.0000x reference)
//
#include <hip/hip_runtime.h>
#include <stdint.h>

#define IC   4096
#define BLK  256
#define CPL  16     // float4 chunks per lane: 16 chunks * 4 elems * 64 lanes = 4096

// ---- in-wave reductions (64 lanes), result in all lanes ----
__device__ __forceinline__ double wsum_d(double v) {
    #pragma unroll
    for (int off = 32; off; off >>= 1) v += __shfl_xor(v, off);
    return v;
}
__device__ __forceinline__ int wsum_i(int v) {
    #pragma unroll
    for (int off = 32; off; off >>= 1) v += __shfl_xor(v, off);
    return v;
}

__global__ __launch_bounds__(BLK, 4) void binarize_kernel(
    const float* __restrict__ x,
    const uint8_t* __restrict__ mask,
    float* __restrict__ out)
{
    const int lane = threadIdx.x & 63;
    const int wid  = threadIdx.x >> 6;
    const int row  = blockIdx.x * (BLK / 64) + wid;   // one row per wave

    // ---- mask dtype detection (wave-uniform, L2-hot probe) ----
    // int32 0/1 mask: first 64 words all <= 1. bool bytes: 4 packed random
    // 0/1 bytes -> some word > 1 w.p. 1-(1/8)^64.
    const uint32_t probe = ((const uint32_t*)mask)[lane];
    const bool mask_is_bytes = __any(probe > 1u);

    const float* xr = x + (size_t)row * IC;

    // ---- load row: lane L owns elems {i*256 + L*4 + k}, i<16, k<4 ----
    float4 xf[CPL];
    #pragma unroll
    for (int i = 0; i < CPL; ++i)
        xf[i] = ((const float4*)xr)[i * 64 + lane];

    // ---- mask -> 64-bit per-lane bitmask ----
    uint64_t bm = 0;
    if (mask_is_bytes) {
        const uint32_t* mr = (const uint32_t*)(mask + (size_t)row * IC);
        uint32_t mw[CPL];
        #pragma unroll
        for (int i = 0; i < CPL; ++i) mw[i] = mr[i * 64 + lane];
        #pragma unroll
        for (int i = 0; i < CPL; ++i) {
            uint64_t b = 0;
            if (mw[i] & 0x000000ffu) b |= 1ull;
            if (mw[i] & 0x0000ff00u) b |= 2ull;
            if (mw[i] & 0x00ff0000u) b |= 4ull;
            if (mw[i] & 0xff000000u) b |= 8ull;
            bm |= b << (i * 4);
        }
    } else {
        const int4* mr = (const int4*)mask + (size_t)row * (IC / 4);
        #pragma unroll
        for (int i = 0; i < CPL; ++i) {
            int4 m4 = mr[i * 64 + lane];
            uint64_t b = 0;
            if (m4.x) b |= 1ull;
            if (m4.y) b |= 2ull;
            if (m4.z) b |= 4ull;
            if (m4.w) b |= 8ull;
            bm |= b << (i * 4);
        }
    }

    // ---- round 1: masked sum (fp64) + count (popcount) ----
    double s = 0.0;
    #pragma unroll
    for (int i = 0; i < CPL; ++i) {
        const float e[4] = {xf[i].x, xf[i].y, xf[i].z, xf[i].w};
        #pragma unroll
        for (int k = 0; k < 4; ++k)
            if ((bm >> (i * 4 + k)) & 1ull) s += (double)e[k];
    }
    s = wsum_d(s);
    const int cnt = wsum_i(__popcll(bm));

    const double dc    = (double)((cnt > 0) ? cnt : 1);
    const double mean1 = (cnt > 0) ? (s / dc) : 0.0;

    // ---- round 2: sa = masked sum |x-mean1|, pn = masked sum sign(x-mean1) ----
    double sa = 0.0;
    int    pn = 0;
    #pragma unroll
    for (int i = 0; i < CPL; ++i) {
        const float e[4] = {xf[i].x, xf[i].y, xf[i].z, xf[i].w};
        #pragma unroll
        for (int k = 0; k < 4; ++k) {
            if ((bm >> (i * 4 + k)) & 1ull) {
                const double ce = (double)e[k] - mean1;
                sa += fabs(ce);
                pn += (ce > 0.0) ? 1 : ((ce < 0.0) ? -1 : 0);
            }
        }
    }
    sa = wsum_d(sa);
    pn = wsum_i(pn);

    const double scale1 = (cnt > 0) ? (sa / dc) : 0.0;
    // analytic mean2: sum(r2) = (s - c*mean1) - scale1*pn   (exact identity)
    const double s2    = (s - dc * mean1) - scale1 * (double)pn;
    const double mean2 = (cnt > 0) ? (s2 / dc) : 0.0;

    // ---- round 3: sd = masked sum |r2 - mean2| ----
    double sd = 0.0;
    #pragma unroll
    for (int i = 0; i < CPL; ++i) {
        const float e[4] = {xf[i].x, xf[i].y, xf[i].z, xf[i].w};
        #pragma unroll
        for (int k = 0; k < 4; ++k) {
            if ((bm >> (i * 4 + k)) & 1ull) {
                const double xd = (double)e[k];
                const double ce = xd - mean1;
                const double t1 = (ce > 0.0) ? scale1 : ((ce < 0.0) ? -scale1 : 0.0);
                const double b1 = t1 + mean1;      // ref association
                const double r2 = xd - b1;
                sd += fabs(r2 - mean2);
            }
        }
    }
    sd = wsum_d(sd);
    const double scale2 = (cnt > 0) ? (sd / dc) : 0.0;

    // ---- epilogue: out = (b1 + b2) on mask, 0 elsewhere ----
    float* orow = out + (size_t)row * IC;
    #pragma unroll
    for (int i = 0; i < CPL; ++i) {
        const float e[4] = {xf[i].x, xf[i].y, xf[i].z, xf[i].w};
        float4 o;
        float* op = &o.x;
        #pragma unroll
        for (int k = 0; k < 4; ++k) {
            if ((bm >> (i * 4 + k)) & 1ull) {
                const double xd = (double)e[k];
                const double ce = xd - mean1;
                const double t1 = (ce > 0.0) ? scale1 : ((ce < 0.0) ? -scale1 : 0.0);
                const double b1 = t1 + mean1;
                const double r2 = xd - b1;
                const double c2 = r2 - mean2;
                const double t2 = (c2 > 0.0) ? scale2 : ((c2 < 0.0) ? -scale2 : 0.0);
                const double b2 = t2 + mean2;
                op[k] = (float)(b1 + b2);
            } else {
                op[k] = 0.0f;
            }
        }
        ((float4*)orow)[i * 64 + lane] = o;
    }
}

extern "C" void kernel_launch(void* const* d_in, const int* in_sizes, int n_in,
                              void* d_out, int out_size, void* d_ws, size_t ws_size,
                              hipStream_t stream) {
    const float*   x    = (const float*)d_in[0];
    const uint8_t* mask = (const uint8_t*)d_in[1];
    float*         out  = (float*)d_out;

    const int rows = in_sizes[0] / IC;     // 11008
    const int grid = rows / (BLK / 64);    // 4 rows per block
    binarize_kernel<<<grid, BLK, 0, stream>>>(x, mask, out);
}

// Round 4
// 497.911 us; speedup vs baseline: 1.2084x; 1.2084x over previous
//
#include <hip/hip_runtime.h>
#include <stdint.h>

#define IC   4096
#define BLK  256
#define CPL  16     // float4 chunks per lane: 16 chunks * 4 elems * 64 lanes = 4096

// ---- in-wave reductions (64 lanes), result in all lanes ----
__device__ __forceinline__ double wsum_d(double v) {
    #pragma unroll
    for (int off = 32; off; off >>= 1) v += __shfl_xor(v, off);
    return v;
}
__device__ __forceinline__ int wsum_i(int v) {
    #pragma unroll
    for (int off = 32; off; off >>= 1) v += __shfl_xor(v, off);
    return v;
}

// NOTE: no min-waves clamp! R3 used __launch_bounds__(256,4) -> 64-VGPR budget
// -> full row cache spilled to scratch -> 700 MB of HBM spill traffic.
__global__ __launch_bounds__(BLK) void binarize_kernel(
    const float* __restrict__ x,
    const uint8_t* __restrict__ mask,
    float* __restrict__ out)
{
    const int lane = threadIdx.x & 63;
    const int wid  = threadIdx.x >> 6;
    const int row  = blockIdx.x * (BLK / 64) + wid;   // one row per wave

    // ---- mask dtype detection (wave-uniform, L2-hot probe) ----
    // int32 0/1 mask: first 64 words all <= 1. bool bytes: 4 packed random
    // 0/1 bytes -> some word > 1 w.p. 1-(1/8)^64.
    const uint32_t probe = ((const uint32_t*)mask)[lane];
    const bool mask_is_bytes = __any(probe > 1u);

    const float* xr = x + (size_t)row * IC;

    // ---- load row: lane L owns elems {i*256 + L*4 + k}, i<16, k<4 ----
    float4 xf[CPL];
    #pragma unroll
    for (int i = 0; i < CPL; ++i)
        xf[i] = ((const float4*)xr)[i * 64 + lane];

    // ---- mask -> 64-bit per-lane bitmask ----
    uint64_t bm = 0;
    if (mask_is_bytes) {
        const uint32_t* mr = (const uint32_t*)(mask + (size_t)row * IC);
        #pragma unroll
        for (int i = 0; i < CPL; ++i) {
            const uint32_t w = mr[i * 64 + lane];
            uint64_t b = 0;
            if (w & 0x000000ffu) b |= 1ull;
            if (w & 0x0000ff00u) b |= 2ull;
            if (w & 0x00ff0000u) b |= 4ull;
            if (w & 0xff000000u) b |= 8ull;
            bm |= b << (i * 4);
        }
    } else {
        const int4* mr = (const int4*)mask + (size_t)row * (IC / 4);
        #pragma unroll
        for (int i = 0; i < CPL; ++i) {
            int4 m4 = mr[i * 64 + lane];
            uint64_t b = 0;
            if (m4.x) b |= 1ull;
            if (m4.y) b |= 2ull;
            if (m4.z) b |= 4ull;
            if (m4.w) b |= 8ull;
            bm |= b << (i * 4);
        }
    }

    // ---- round 1: masked sum (fp64) + count (popcount) ----
    double s = 0.0;
    #pragma unroll
    for (int i = 0; i < CPL; ++i) {
        const float e[4] = {xf[i].x, xf[i].y, xf[i].z, xf[i].w};
        #pragma unroll
        for (int k = 0; k < 4; ++k)
            if ((bm >> (i * 4 + k)) & 1ull) s += (double)e[k];
    }
    s = wsum_d(s);
    const int cnt = wsum_i(__popcll(bm));

    const double dc    = (double)((cnt > 0) ? cnt : 1);
    const double mean1 = (cnt > 0) ? (s / dc) : 0.0;

    // ---- round 2: sa = masked sum |x-mean1|, pn = masked sum sign(x-mean1) ----
    double sa = 0.0;
    int    pn = 0;
    #pragma unroll
    for (int i = 0; i < CPL; ++i) {
        const float e[4] = {xf[i].x, xf[i].y, xf[i].z, xf[i].w};
        #pragma unroll
        for (int k = 0; k < 4; ++k) {
            if ((bm >> (i * 4 + k)) & 1ull) {
                const double ce = (double)e[k] - mean1;
                sa += fabs(ce);
                pn += (ce > 0.0) ? 1 : ((ce < 0.0) ? -1 : 0);
            }
        }
    }
    sa = wsum_d(sa);
    pn = wsum_i(pn);

    const double scale1 = (cnt > 0) ? (sa / dc) : 0.0;
    // analytic mean2: sum(r2) = (s - c*mean1) - scale1*pn   (exact identity)
    const double s2    = (s - dc * mean1) - scale1 * (double)pn;
    const double mean2 = (cnt > 0) ? (s2 / dc) : 0.0;

    // ---- round 3: sd = masked sum |r2 - mean2| ----
    double sd = 0.0;
    #pragma unroll
    for (int i = 0; i < CPL; ++i) {
        const float e[4] = {xf[i].x, xf[i].y, xf[i].z, xf[i].w};
        #pragma unroll
        for (int k = 0; k < 4; ++k) {
            if ((bm >> (i * 4 + k)) & 1ull) {
                const double xd = (double)e[k];
                const double ce = xd - mean1;
                const double t1 = (ce > 0.0) ? scale1 : ((ce < 0.0) ? -scale1 : 0.0);
                const double b1 = t1 + mean1;      // ref association
                const double r2 = xd - b1;
                sd += fabs(r2 - mean2);
            }
        }
    }
    sd = wsum_d(sd);
    const double scale2 = (cnt > 0) ? (sd / dc) : 0.0;

    // ---- epilogue: out = (b1 + b2) on mask, 0 elsewhere ----
    float* orow = out + (size_t)row * IC;
    #pragma unroll
    for (int i = 0; i < CPL; ++i) {
        const float e[4] = {xf[i].x, xf[i].y, xf[i].z, xf[i].w};
        float4 o;
        float* op = &o.x;
        #pragma unroll
        for (int k = 0; k < 4; ++k) {
            if ((bm >> (i * 4 + k)) & 1ull) {
                const double xd = (double)e[k];
                const double ce = xd - mean1;
                const double t1 = (ce > 0.0) ? scale1 : ((ce < 0.0) ? -scale1 : 0.0);
                const double b1 = t1 + mean1;
                const double r2 = xd - b1;
                const double c2 = r2 - mean2;
                const double t2 = (c2 > 0.0) ? scale2 : ((c2 < 0.0) ? -scale2 : 0.0);
                const double b2 = t2 + mean2;
                op[k] = (float)(b1 + b2);
            } else {
                op[k] = 0.0f;
            }
        }
        ((float4*)orow)[i * 64 + lane] = o;
    }
}

extern "C" void kernel_launch(void* const* d_in, const int* in_sizes, int n_in,
                              void* d_out, int out_size, void* d_ws, size_t ws_size,
                              hipStream_t stream) {
    const float*   x    = (const float*)d_in[0];
    const uint8_t* mask = (const uint8_t*)d_in[1];
    float*         out  = (float*)d_out;

    const int rows = in_sizes[0] / IC;     // 11008
    const int grid = rows / (BLK / 64);    // 4 rows per block
    binarize_kernel<<<grid, BLK, 0, stream>>>(x, mask, out);
}

// Round 5
// 403.571 us; speedup vs baseline: 1.4909x; 1.2338x over previous
//
#include <hip/hip_runtime.h>
#include <stdint.h>

#define IC   4096
#define BLK  256
#define CPT  4     // float4 chunks per thread: 4 * 4 elems * 256 thr = 4096

// ---- in-wave reductions (64 lanes), result broadcast to all lanes ----
__device__ __forceinline__ double wsum_d(double v) {
    #pragma unroll
    for (int off = 32; off; off >>= 1) v += __shfl_xor(v, off);
    return v;
}
__device__ __forceinline__ int wsum_i(int v) {
    #pragma unroll
    for (int off = 32; off; off >>= 1) v += __shfl_xor(v, off);
    return v;
}

// Block-per-row, 16 elems/thread: x-cache = 16 VGPRs (R4's wave-per-row needed
// 64 and capped occupancy at 3 waves/SIMD -> latency-bound at 244 us).
__global__ __launch_bounds__(BLK) void binarize_kernel(
    const float* __restrict__ x,
    const uint8_t* __restrict__ mask,
    float* __restrict__ out)
{
    __shared__ double sm_d[4];
    __shared__ int    sm_i[4];

    const int tid  = threadIdx.x;
    const int lane = tid & 63;
    const int wid  = tid >> 6;
    const int row  = blockIdx.x;

    // ---- mask dtype detection (uniform; bytes: some of first 64 words > 1) ----
    const uint32_t probe = ((const uint32_t*)mask)[lane];
    const bool mask_is_bytes = __any(probe > 1u);

    const float* xr = x + (size_t)row * IC;

    float4 xf[CPT];
    #pragma unroll
    for (int i = 0; i < CPT; ++i)
        xf[i] = ((const float4*)xr)[i * BLK + tid];

    // ---- mask -> 16-bit per-thread bitmask ----
    uint32_t bm = 0;
    if (mask_is_bytes) {
        const uint32_t* mr = (const uint32_t*)(mask + (size_t)row * IC);
        #pragma unroll
        for (int i = 0; i < CPT; ++i) {
            const uint32_t w = mr[i * BLK + tid];   // 4 bytes, each 0/1
            // bytes(0/1) -> 4 bits, elem k at bit k: (w * 0x01020408) >> 24
            bm |= (((w * 0x01020408u) >> 24) & 0xFu) << (4 * i);
        }
    } else {
        const int4* mr = (const int4*)mask + (size_t)row * (IC / 4);
        #pragma unroll
        for (int i = 0; i < CPT; ++i) {
            int4 m4 = mr[i * BLK + tid];
            uint32_t b = (m4.x ? 1u : 0u) | (m4.y ? 2u : 0u)
                       | (m4.z ? 4u : 0u) | (m4.w ? 8u : 0u);
            bm |= b << (4 * i);
        }
    }

    // ---- round 1: masked sum (fp64, 4-way ILP) + popcount ----
    double a0 = 0.0, a1 = 0.0, a2 = 0.0, a3 = 0.0;
    #pragma unroll
    for (int i = 0; i < CPT; ++i) {
        a0 += (double)(((bm >> (4*i + 0)) & 1u) ? xf[i].x : 0.0f);
        a1 += (double)(((bm >> (4*i + 1)) & 1u) ? xf[i].y : 0.0f);
        a2 += (double)(((bm >> (4*i + 2)) & 1u) ? xf[i].z : 0.0f);
        a3 += (double)(((bm >> (4*i + 3)) & 1u) ? xf[i].w : 0.0f);
    }
    {
        double sw = wsum_d((a0 + a1) + (a2 + a3));
        int    cw = wsum_i(__popc(bm));
        if (lane == 0) { sm_d[wid] = sw; sm_i[wid] = cw; }
    }
    __syncthreads();
    const double s   = (sm_d[0] + sm_d[1]) + (sm_d[2] + sm_d[3]);
    const int    cnt = (sm_i[0] + sm_i[1]) + (sm_i[2] + sm_i[3]);
    __syncthreads();

    const bool   has   = (cnt > 0);
    const double dc    = (double)(has ? cnt : 1);
    const double mean1 = has ? (s / dc) : 0.0;

    // ---- round 2: sa = sum |x-mean1| (masked), pn = sum sign(x-mean1) ----
    double p0 = 0.0, p1 = 0.0, p2 = 0.0, p3 = 0.0;
    int q = 0;
    #pragma unroll
    for (int i = 0; i < CPT; ++i) {
        const float e[4] = {xf[i].x, xf[i].y, xf[i].z, xf[i].w};
        {
            const bool b = (bm >> (4*i + 0)) & 1u;
            const double ce = (double)e[0] - mean1;
            p0 += b ? fabs(ce) : 0.0;
            q  += b ? (int)(ce > 0.0) - (int)(ce < 0.0) : 0;
        }
        {
            const bool b = (bm >> (4*i + 1)) & 1u;
            const double ce = (double)e[1] - mean1;
            p1 += b ? fabs(ce) : 0.0;
            q  += b ? (int)(ce > 0.0) - (int)(ce < 0.0) : 0;
        }
        {
            const bool b = (bm >> (4*i + 2)) & 1u;
            const double ce = (double)e[2] - mean1;
            p2 += b ? fabs(ce) : 0.0;
            q  += b ? (int)(ce > 0.0) - (int)(ce < 0.0) : 0;
        }
        {
            const bool b = (bm >> (4*i + 3)) & 1u;
            const double ce = (double)e[3] - mean1;
            p3 += b ? fabs(ce) : 0.0;
            q  += b ? (int)(ce > 0.0) - (int)(ce < 0.0) : 0;
        }
    }
    {
        double sw = wsum_d((p0 + p1) + (p2 + p3));
        int    qw = wsum_i(q);
        if (lane == 0) { sm_d[wid] = sw; sm_i[wid] = qw; }
    }
    __syncthreads();
    const double sa = (sm_d[0] + sm_d[1]) + (sm_d[2] + sm_d[3]);
    const int    pn = (sm_i[0] + sm_i[1]) + (sm_i[2] + sm_i[3]);
    __syncthreads();

    const double scale1 = has ? (sa / dc) : 0.0;
    // analytic mean2: sum(r2) = (s - c*mean1) - scale1*pn  (exact identity,
    // HW-validated bit-exact vs np ref in R4)
    const double s2    = (s - dc * mean1) - scale1 * (double)pn;
    const double mean2 = has ? (s2 / dc) : 0.0;

    // b1 candidates (ref association: sign*scale + mean, one rounding)
    const double Ap = scale1 + mean1;
    const double Am = -scale1 + mean1;
    const double A0 = mean1;

    // ---- round 3: sd = sum |(x - b1) - mean2| (masked) ----
    double d0 = 0.0, d1 = 0.0, d2 = 0.0, d3 = 0.0;
    #pragma unroll
    for (int i = 0; i < CPT; ++i) {
        const float e[4] = {xf[i].x, xf[i].y, xf[i].z, xf[i].w};
        {
            const bool b = (bm >> (4*i + 0)) & 1u;
            const double xd = (double)e[0];
            const double A  = (xd > mean1) ? Ap : ((xd < mean1) ? Am : A0);
            const double c2 = (xd - A) - mean2;   // ref-exact two-step rounding
            d0 += b ? fabs(c2) : 0.0;
        }
        {
            const bool b = (bm >> (4*i + 1)) & 1u;
            const double xd = (double)e[1];
            const double A  = (xd > mean1) ? Ap : ((xd < mean1) ? Am : A0);
            const double c2 = (xd - A) - mean2;
            d1 += b ? fabs(c2) : 0.0;
        }
        {
            const bool b = (bm >> (4*i + 2)) & 1u;
            const double xd = (double)e[2];
            const double A  = (xd > mean1) ? Ap : ((xd < mean1) ? Am : A0);
            const double c2 = (xd - A) - mean2;
            d2 += b ? fabs(c2) : 0.0;
        }
        {
            const bool b = (bm >> (4*i + 3)) & 1u;
            const double xd = (double)e[3];
            const double A  = (xd > mean1) ? Ap : ((xd < mean1) ? Am : A0);
            const double c2 = (xd - A) - mean2;
            d3 += b ? fabs(c2) : 0.0;
        }
    }
    {
        double sw = wsum_d((d0 + d1) + (d2 + d3));
        if (lane == 0) sm_d[wid] = sw;
    }
    __syncthreads();
    const double sd = (sm_d[0] + sm_d[1]) + (sm_d[2] + sm_d[3]);

    const double scale2 = has ? (sd / dc) : 0.0;
    const double Bp = scale2 + mean2;
    const double Bm = -scale2 + mean2;
    const double B0 = mean2;

    // ---- epilogue: out = (b1 + b2) on mask, 0 elsewhere ----
    float* orow = out + (size_t)row * IC;
    #pragma unroll
    for (int i = 0; i < CPT; ++i) {
        const float e[4] = {xf[i].x, xf[i].y, xf[i].z, xf[i].w};
        float4 o;
        float* op = &o.x;
        #pragma unroll
        for (int k = 0; k < 4; ++k) {
            const bool b = (bm >> (4*i + k)) & 1u;
            const double xd = (double)e[k];
            const double A  = (xd > mean1) ? Ap : ((xd < mean1) ? Am : A0);
            const double c2 = (xd - A) - mean2;
            const double B  = (c2 > 0.0) ? Bp : ((c2 < 0.0) ? Bm : B0);
            const float  r  = (float)(A + B);     // == (float)(b1 + b2), ref-exact
            op[k] = b ? r : 0.0f;
        }
        ((float4*)orow)[i * BLK + tid] = o;
    }
}

extern "C" void kernel_launch(void* const* d_in, const int* in_sizes, int n_in,
                              void* d_out, int out_size, void* d_ws, size_t ws_size,
                              hipStream_t stream) {
    const float*   x    = (const float*)d_in[0];
    const uint8_t* mask = (const uint8_t*)d_in[1];
    float*         out  = (float*)d_out;

    const int rows = in_sizes[0] / IC;   // 11008
    binarize_kernel<<<rows, BLK, 0, stream>>>(x, mask, out);
}